// Round 2
// baseline (1278.290 us; speedup 1.0000x reference)
//
#include <hip/hip_runtime.h>

// Problem constants (match reference setup_inputs)
static constexpr int N_NODES = 100000;
static constexpr int N_EDGES = 3200000;
// DIM = 4

// Pass 1: lt[col[e]] += A_e^T * x[row[e]]
__global__ void __launch_bounds__(256) llt_pass1(
    const float4* __restrict__ x,        // [N_NODES] as float4
    const int* __restrict__ row_idx,     // edge_index[0], int32
    const int* __restrict__ col_idx,     // edge_index[1], int32
    const float4* __restrict__ boo,      // [N_EDGES*4] float4 (4 rows of A per edge)
    float* __restrict__ lt)              // [N_NODES*4]
{
    int e = blockIdx.x * blockDim.x + threadIdx.x;
    if (e >= N_EDGES) return;

    int r = row_idx[e];
    int c = col_idx[e];

    float4 xv = x[r];
    float4 a0 = boo[e * 4 + 0];  // A[0][0..3]
    float4 a1 = boo[e * 4 + 1];  // A[1][0..3]
    float4 a2 = boo[e * 4 + 2];
    float4 a3 = boo[e * 4 + 3];

    // msg[i] = sum_j A[j][i] * x[j]   (A^T x -> column i of A dot x)
    float m0 = a0.x * xv.x + a1.x * xv.y + a2.x * xv.z + a3.x * xv.w;
    float m1 = a0.y * xv.x + a1.y * xv.y + a2.y * xv.z + a3.y * xv.w;
    float m2 = a0.z * xv.x + a1.z * xv.y + a2.z * xv.z + a3.z * xv.w;
    float m3 = a0.w * xv.x + a1.w * xv.y + a2.w * xv.z + a3.w * xv.w;

    float* dst = lt + (size_t)c * 4;
    atomicAdd(dst + 0, m0);
    atomicAdd(dst + 1, m1);
    atomicAdd(dst + 2, m2);
    atomicAdd(dst + 3, m3);
}

// Pass 2: out[row[e]] += A_e * lt[col[e]]
__global__ void __launch_bounds__(256) llt_pass2(
    const float4* __restrict__ lt,       // [N_NODES] as float4
    const int* __restrict__ row_idx,
    const int* __restrict__ col_idx,
    const float4* __restrict__ boo,
    float* __restrict__ out)             // [N_NODES*4]
{
    int e = blockIdx.x * blockDim.x + threadIdx.x;
    if (e >= N_EDGES) return;

    int r = row_idx[e];
    int c = col_idx[e];

    float4 lv = lt[c];
    float4 a0 = boo[e * 4 + 0];
    float4 a1 = boo[e * 4 + 1];
    float4 a2 = boo[e * 4 + 2];
    float4 a3 = boo[e * 4 + 3];

    // msg[i] = sum_j A[i][j] * lt[j]  (row i of A dot lt)
    float m0 = a0.x * lv.x + a0.y * lv.y + a0.z * lv.z + a0.w * lv.w;
    float m1 = a1.x * lv.x + a1.y * lv.y + a1.z * lv.z + a1.w * lv.w;
    float m2 = a2.x * lv.x + a2.y * lv.y + a2.z * lv.z + a2.w * lv.w;
    float m3 = a3.x * lv.x + a3.y * lv.y + a3.z * lv.z + a3.w * lv.w;

    float* dst = out + (size_t)r * 4;
    atomicAdd(dst + 0, m0);
    atomicAdd(dst + 1, m1);
    atomicAdd(dst + 2, m2);
    atomicAdd(dst + 3, m3);
}

extern "C" void kernel_launch(void* const* d_in, const int* in_sizes, int n_in,
                              void* d_out, int out_size, void* d_ws, size_t ws_size,
                              hipStream_t stream) {
    const float4* x = (const float4*)d_in[0];          // [100000,4] f32
    const int* edge_index = (const int*)d_in[1];       // [2, 3200000] delivered as int32
    const float4* boo = (const float4*)d_in[2];        // [3200000,4,4] f32

    const int* row_idx = edge_index;                   // edge_index[0]
    const int* col_idx = edge_index + N_EDGES;         // edge_index[1]

    float* out = (float*)d_out;        // [100000*4] f32
    float* lt = (float*)d_ws;          // scratch: 400000 f32 = 1.6 MB

    // Zero accumulators (harness poisons d_out/d_ws; we accumulate via atomics)
    hipMemsetAsync(lt, 0, (size_t)N_NODES * 4 * sizeof(float), stream);
    hipMemsetAsync(out, 0, (size_t)N_NODES * 4 * sizeof(float), stream);

    const int block = 256;
    const int grid = (N_EDGES + block - 1) / block;

    llt_pass1<<<grid, block, 0, stream>>>(x, row_idx, col_idx, boo, lt);
    llt_pass2<<<grid, block, 0, stream>>>((const float4*)lt, row_idx, col_idx, boo, out);
}

// Round 3
// 328.186 us; speedup vs baseline: 3.8950x; 3.8950x over previous
//
#include <hip/hip_runtime.h>

// Problem constants (match reference setup_inputs)
static constexpr int N_NODES = 100000;
static constexpr int N_EDGES = 3200000;
// DIM = 4

// 4 threads per edge: thread (e, i) computes component i of the edge message
// and issues ONE atomicAdd. The 4 lanes of an edge are adjacent in the wave,
// so their 4 atomic destinations (16 contiguous bytes, within one 32B sector)
// sit in a single atomic wave-instruction -> hardware can merge them into one
// sector transaction instead of 4.

// Pass 1: lt[col[e]][i] += sum_j A_e[j][i] * x[row[e]][j]   (A^T x)
__global__ void __launch_bounds__(256) llt_pass1(
    const float* __restrict__ x,        // [N_NODES*4]
    const int* __restrict__ row_idx,    // edge_index[0], int32
    const int* __restrict__ col_idx,    // edge_index[1], int32
    const float* __restrict__ boo,      // [N_EDGES*16]
    float* __restrict__ lt)             // [N_NODES*4]
{
    int t = blockIdx.x * blockDim.x + threadIdx.x;
    if (t >= N_EDGES * 4) return;
    int e = t >> 2;
    int i = t & 3;

    int r = row_idx[e];
    int c = col_idx[e];

    const float* A = boo + (size_t)e * 16;
    const float* xv = x + (size_t)r * 4;

    // column i of A dot x
    float m = A[0 * 4 + i] * xv[0]
            + A[1 * 4 + i] * xv[1]
            + A[2 * 4 + i] * xv[2]
            + A[3 * 4 + i] * xv[3];

    atomicAdd(lt + (size_t)c * 4 + i, m);
}

// Pass 2: out[row[e]][i] += sum_j A_e[i][j] * lt[col[e]][j]  (A lt)
__global__ void __launch_bounds__(256) llt_pass2(
    const float4* __restrict__ lt,      // [N_NODES] as float4
    const int* __restrict__ row_idx,
    const int* __restrict__ col_idx,
    const float4* __restrict__ boo,     // [N_EDGES*4] float4 rows
    float* __restrict__ out)            // [N_NODES*4]
{
    int t = blockIdx.x * blockDim.x + threadIdx.x;
    if (t >= N_EDGES * 4) return;
    int e = t >> 2;
    int i = t & 3;

    int r = row_idx[e];
    int c = col_idx[e];

    float4 arow = boo[(size_t)e * 4 + i];  // row i of A, contiguous 16B
    float4 lv = lt[c];

    float m = arow.x * lv.x + arow.y * lv.y + arow.z * lv.z + arow.w * lv.w;

    atomicAdd(out + (size_t)r * 4 + i, m);
}

extern "C" void kernel_launch(void* const* d_in, const int* in_sizes, int n_in,
                              void* d_out, int out_size, void* d_ws, size_t ws_size,
                              hipStream_t stream) {
    const float* x = (const float*)d_in[0];          // [100000,4] f32
    const int* edge_index = (const int*)d_in[1];     // [2, 3200000] int32
    const float* boo = (const float*)d_in[2];        // [3200000,4,4] f32

    const int* row_idx = edge_index;                 // edge_index[0]
    const int* col_idx = edge_index + N_EDGES;       // edge_index[1]

    float* out = (float*)d_out;        // [100000*4] f32
    float* lt = (float*)d_ws;          // scratch: 400000 f32 = 1.6 MB

    hipMemsetAsync(lt, 0, (size_t)N_NODES * 4 * sizeof(float), stream);
    hipMemsetAsync(out, 0, (size_t)N_NODES * 4 * sizeof(float), stream);

    const int block = 256;
    const int grid = (N_EDGES * 4 + block - 1) / block;  // 4 threads per edge

    llt_pass1<<<grid, block, 0, stream>>>(x, row_idx, col_idx, boo, lt);
    llt_pass2<<<grid, block, 0, stream>>>((const float4*)lt, row_idx, col_idx,
                                          (const float4*)boo, out);
}